// Round 5
// baseline (366.704 us; speedup 1.0000x reference)
//
#include <hip/hip_runtime.h>
#include <hip/hip_bf16.h>

typedef unsigned long long u64;
typedef unsigned int u32;

#define NTOT    54560   // anchors per batch (r + i)
#define NMOD    27280   // anchors per modality
#define BATCH   16
#define KPAD    1024
#define MAXD    1000
#define NBIN    4096    // score-bits >> 18 (max possible bin 0x3F8 = 1016)
#define CAND    6144    // candidate cap (u64, 48KB in fixup LDS)
#define NCHUNK  7       // key chunks per batch (7 * 8192 >= NTOT)

struct Ptrs { const float* p[30]; };

// ---------------- workspace layout (16B aligned) ----------------
constexpr size_t SZ_KEY    = (size_t)BATCH * NTOT * 8;        // 6.98 MB
constexpr size_t SZ_TOPK   = (size_t)BATCH * KPAD * 8;
constexpr size_t SZ_TRAW   = (size_t)BATCH * KPAD * 16;
constexpr size_t SZ_T1     = (size_t)BATCH * KPAD * 4;
constexpr size_t SZ_MAXC   = (size_t)BATCH * 32 * 4;
constexpr size_t SZ_VALID  = (size_t)BATCH * 32 * 4;
constexpr size_t SZ_MASK   = (size_t)BATCH * KPAD * 32 * 4;   // 2 MB
constexpr size_t SZ_GHIST  = (size_t)BATCH * NBIN * 4;        // 256 KB (merged + prefixes)
constexpr size_t SZ_GHISTP = (size_t)BATCH * NCHUNK * NBIN * 4; // 1.75 MB partials
constexpr size_t SZ_GB1    = 256;                             // 16 ints + pad
constexpr size_t SZ_GCAND  = (size_t)BATCH * CAND * 8;        // 768 KB

constexpr size_t OFF_KEY    = 0;
constexpr size_t OFF_TOPK   = OFF_KEY   + SZ_KEY;
constexpr size_t OFF_TRAW   = OFF_TOPK  + SZ_TOPK;
constexpr size_t OFF_TSCORE = OFF_TRAW  + SZ_TRAW;
constexpr size_t OFF_TCLSF  = OFF_TSCORE+ SZ_T1;
constexpr size_t OFF_MAXC   = OFF_TCLSF + SZ_T1;
constexpr size_t OFF_VALID  = OFF_MAXC  + SZ_MAXC;
constexpr size_t OFF_MASK   = OFF_VALID + SZ_VALID;
constexpr size_t OFF_GHIST  = OFF_MASK  + SZ_MASK;
constexpr size_t OFF_GHISTP = OFF_GHIST + SZ_GHIST;
constexpr size_t OFF_GB1    = OFF_GHISTP+ SZ_GHISTP;
constexpr size_t OFF_GCAND  = OFF_GB1   + SZ_GB1;

__device__ inline void level_of(int nm, int& l, int& pos, int& w, int& s, int& hw) {
    if (nm < 20480)      { l = 0; pos = nm;         w = 160; s = 8;   hw = 20480; }
    else if (nm < 25600) { l = 1; pos = nm - 20480; w = 80;  s = 16;  hw = 5120; }
    else if (nm < 26880) { l = 2; pos = nm - 25600; w = 40;  s = 32;  hw = 1280; }
    else if (nm < 27200) { l = 3; pos = nm - 26880; w = 20;  s = 64;  hw = 320; }
    else                 { l = 4; pos = nm - 27200; w = 10;  s = 128; hw = 80; }
}

__device__ inline float sigm(float x) { return 1.0f / (1.0f + expf(-x)); }

// async global->LDS DMA, 16B per lane; LDS dest = uniform base + lane*16
__device__ inline void ld_lds16(const float* g, float* l) {
    __builtin_amdgcn_global_load_lds(
        (const __attribute__((address_space(1))) void*)g,
        (__attribute__((address_space(3))) void*)l, 16, 0, 0);
}

// ---------------- kernel 1: decode (512-anchor LDS chunks + quad-split tail) ----------------
// R1-proven version (global_load_lds DMA). The R4 register rewrite measured
// slower (reg-staging: per-channel 64-bit addr chains + VGPR round trip).
__global__ __launch_bounds__(128)
void decode_kernel(Ptrs ptrs, u64* __restrict__ keyAll) {
    __shared__ float lds[21 * 512];     // 42KB (unused by tail blocks)
    int cc = blockIdx.x;                // 0..99 LDS path, 100..126 tail
    int b = blockIdx.y;

    if (cc >= 100) {
        int t = (cc - 100) * 128 + threadIdx.x;   // 0..3359
        if (t >= 3360) return;
        int mod = t / 1680;
        int tm = t % 1680;
        int q = t & 3;                            // 1680 % 4 == 0
        int nm = 25600 + (tm & ~3);
        int l, pos, w, s, hw;
        level_of(nm, l, pos, w, s, hw);
        (void)w; (void)s;
        const float* clsP = ptrs.p[mod * 15 + l];
        const float* cntP = ptrs.p[mod * 15 + 5 + l];
        const float4* cb = (const float4*)(clsP + (size_t)b * 20 * hw + pos);
        int hw4 = hw >> 2;
        int c0 = q * 5;
        float4 v[5];
        #pragma unroll
        for (int c = 0; c < 5; ++c) v[c] = cb[(size_t)(c0 + c) * hw4];
        float4 cv = *(const float4*)(cntP + (size_t)b * hw + pos);
        float4 mx = v[0];
        #pragma unroll
        for (int c = 1; c < 5; ++c) {
            mx.x = fmaxf(mx.x, v[c].x); mx.y = fmaxf(mx.y, v[c].y);
            mx.z = fmaxf(mx.z, v[c].z); mx.w = fmaxf(mx.w, v[c].w);
        }
        mx.x = fmaxf(mx.x, __shfl_xor(mx.x, 1));
        mx.y = fmaxf(mx.y, __shfl_xor(mx.y, 1));
        mx.z = fmaxf(mx.z, __shfl_xor(mx.z, 1));
        mx.w = fmaxf(mx.w, __shfl_xor(mx.w, 1));
        mx.x = fmaxf(mx.x, __shfl_xor(mx.x, 2));
        mx.y = fmaxf(mx.y, __shfl_xor(mx.y, 2));
        mx.z = fmaxf(mx.z, __shfl_xor(mx.z, 2));
        mx.w = fmaxf(mx.w, __shfl_xor(mx.w, 2));
        float ma = (q & 1) ? ((q & 2) ? mx.w : mx.y) : ((q & 2) ? mx.z : mx.x);
        float ca = (q & 1) ? ((q & 2) ? cv.w : cv.y) : ((q & 2) ? cv.z : cv.x);
        u32 sb = __float_as_uint(sqrtf(__fmul_rn(sigm(ma), sigm(ca))));
        int n = mod * NMOD + nm + q;
        keyAll[(size_t)b * NTOT + n] = ((u64)sb << 16) | (u64)(65535 - n);
        return;
    }

    int mod = cc / 50, c = cc % 50;
    int l     = (c < 40) ? 0 : 1;
    int hw    = (c < 40) ? 20480 : 5120;
    int pos0  = (c < 40) ? c * 512 : (c - 40) * 512;
    int nmb   = (l == 0) ? pos0 : 20480 + pos0;
    const float* clsP = ptrs.p[mod * 15 + l];
    const float* cntP = ptrs.p[mod * 15 + 5 + l];
    int wave = threadIdx.x >> 6, lane = threadIdx.x & 63;

    const float* cbase = clsP + (size_t)b * 20 * hw + pos0 + wave * 256 + lane * 4;
    float* dbase = lds + wave * 256;
    #pragma unroll
    for (int ch = 0; ch < 20; ++ch)
        ld_lds16(cbase + (size_t)ch * hw, dbase + ch * 512);
    ld_lds16(cntP + (size_t)b * hw + pos0 + wave * 256 + lane * 4, dbase + 20 * 512);
    __syncthreads();

    int t = threadIdx.x;                 // 0..127, anchor group pos0 + 4t
    const float4* l4 = (const float4*)lds;
    float4 mx = l4[t];
    #pragma unroll
    for (int ch = 1; ch < 20; ++ch) {
        float4 v = l4[ch * 128 + t];
        mx.x = fmaxf(mx.x, v.x); mx.y = fmaxf(mx.y, v.y);
        mx.z = fmaxf(mx.z, v.z); mx.w = fmaxf(mx.w, v.w);
    }
    float4 cv = l4[20 * 128 + t];

    int n = mod * NMOD + nmb + t * 4;
    u32 s0 = __float_as_uint(sqrtf(__fmul_rn(sigm(mx.x), sigm(cv.x))));
    u32 s1 = __float_as_uint(sqrtf(__fmul_rn(sigm(mx.y), sigm(cv.y))));
    u32 s2 = __float_as_uint(sqrtf(__fmul_rn(sigm(mx.z), sigm(cv.z))));
    u32 s3 = __float_as_uint(sqrtf(__fmul_rn(sigm(mx.w), sigm(cv.w))));
    ulonglong2* ka2 = (ulonglong2*)(keyAll + (size_t)b * NTOT + n);
    ulonglong2 k01, k23;
    k01.x = ((u64)s0 << 16) | (u64)(65535 - n);
    k01.y = ((u64)s1 << 16) | (u64)(65535 - (n + 1));
    k23.x = ((u64)s2 << 16) | (u64)(65535 - (n + 2));
    k23.y = ((u64)s3 << 16) | (u64)(65535 - (n + 3));
    ka2[0] = k01; ka2[1] = k23;
}

// ---------------- kernel 2a: per-chunk LDS histogram -> global partials ----------------
// 112 blocks (7 chunks x 16 batches): LDS atomics only (16KB hist), coalesced flush.
__global__ __launch_bounds__(1024)
void hist_kernel(const u64* __restrict__ keyAll, u32* __restrict__ ghistP,
                 u32* __restrict__ maxcG) {
    __shared__ u32 shist[NBIN];        // 16KB
    int b = blockIdx.y, chunk = blockIdx.x, tid = threadIdx.x;
    #pragma unroll
    for (int j = 0; j < NBIN / 1024; ++j) shist[tid + j * 1024] = 0u;
    if (chunk == 0 && tid == 0) maxcG[b * 32] = 0u;   // gather's atomicMax baseline
    __syncthreads();

    const u64* keys = keyAll + (size_t)b * NTOT;
    int n0 = chunk * 8192;
    u64 kk[8];
    #pragma unroll
    for (int r = 0; r < 8; ++r) {
        int idx = n0 + r * 1024 + tid;
        kk[r] = (idx < NTOT) ? keys[idx] : ~0ull;
    }
    #pragma unroll
    for (int r = 0; r < 8; ++r)
        if (kk[r] != ~0ull) atomicAdd(&shist[(u32)(kk[r] >> 36)], 1u);
    __syncthreads();

    u32* gp = ghistP + ((size_t)b * NCHUNK + chunk) * NBIN;
    #pragma unroll
    for (int j = 0; j < NBIN / 1024; ++j) gp[tid + j * 1024] = shist[tid + j * 1024];
}

// ---------------- kernel 2b: merge partials (uint4, in-LDS) + reverse scan ----------------
// 16 blocks; merge is 112KB/block of L2/L3-hot data. gh[bin] becomes
// P[bin] = count of keys in bins > bin (segment start). Also finds B1.
__global__ __launch_bounds__(1024)
void scan_kernel(const u32* __restrict__ ghistP, u32* __restrict__ ghist,
                 int* __restrict__ gB1) {
    __shared__ u32 smh[NBIN];          // 16KB merged hist
    __shared__ u32 warep[16];
    __shared__ int sB1;
    int b = blockIdx.x, tid = threadIdx.x;
    int lane = tid & 63, wid = tid >> 6;

    const uint4* gp4 = (const uint4*)(ghistP + (size_t)b * NCHUNK * NBIN);
    uint4 s4 = make_uint4(0u, 0u, 0u, 0u);
    #pragma unroll
    for (int c = 0; c < NCHUNK; ++c) {
        uint4 v = gp4[(size_t)c * (NBIN / 4) + tid];
        s4.x += v.x; s4.y += v.y; s4.z += v.z; s4.w += v.w;
    }
    ((uint4*)smh)[tid] = s4;
    __syncthreads();

    u32 loc[4]; u32 sum = 0;
    #pragma unroll
    for (int j = 0; j < 4; ++j) { loc[j] = smh[NBIN - 1 - (tid * 4 + j)]; sum += loc[j]; }
    u32 v = sum;
    #pragma unroll
    for (int off = 1; off < 64; off <<= 1) {
        u32 t2 = (u32)__shfl_up((int)v, off);
        if (lane >= off) v += t2;
    }
    if (lane == 63) warep[wid] = v;
    __syncthreads();
    if (tid < 16) {
        u32 p = warep[tid];
        #pragma unroll
        for (int off = 1; off < 16; off <<= 1) {
            u32 t2 = (u32)__shfl_up((int)p, off);
            if (tid >= off) p += t2;
        }
        warep[tid] = p;
    }
    __syncthreads();
    u32 incl = v + (wid ? warep[wid - 1] : 0u);
    u32 excl = incl - sum;
    if (excl < (u32)MAXD && incl >= (u32)MAXD) {
        u32 c = excl;
        #pragma unroll
        for (int j = 0; j < 4; ++j) {
            c += loc[j];
            if (c >= (u32)MAXD) { sB1 = NBIN - 1 - (tid * 4 + j); break; }
        }
    }
    u32 run = excl;
    u32* gh = ghist + (size_t)b * NBIN;
    #pragma unroll
    for (int j = 0; j < 4; ++j) {
        int bin = NBIN - 1 - (tid * 4 + j);
        gh[bin] = run;
        run += loc[j];
    }
    __syncthreads();
    if (tid == 0) gB1[b] = sB1;
}

// ---------------- kernel 2c: parallel scatter of candidates ----------------
// One pass over keyAll across 112 blocks; gh[bin] cells advance to segment ends.
// Only ~2K candidates/batch pass the B1 filter -> global atomics negligible here.
__global__ __launch_bounds__(1024)
void scatter_kernel(const u64* __restrict__ keyAll, u32* __restrict__ ghist,
                    const int* __restrict__ gB1, u64* __restrict__ gcand) {
    int b = blockIdx.y, tid = threadIdx.x;
    int n0 = blockIdx.x * 8192;
    int B1 = gB1[b];
    const u64* keys = keyAll + (size_t)b * NTOT;
    u32* gh = ghist + (size_t)b * NBIN;
    u64* gc = gcand + (size_t)b * CAND;
    u64 kk[8];
    #pragma unroll
    for (int r = 0; r < 8; ++r) {
        int idx = n0 + r * 1024 + tid;
        kk[r] = (idx < NTOT) ? keys[idx] : 0ull;   // real keys never 0
    }
    #pragma unroll
    for (int r = 0; r < 8; ++r) {
        if (kk[r] != 0ull && (int)(kk[r] >> 36) >= B1) {
            u32 p = atomicAdd(&gh[(u32)(kk[r] >> 36)], 1u);
            if (p < CAND) gc[p] = kk[r];
        }
    }
}

// ---------------- kernel 2d: in-bin rank fixup -> exact sorted top-MAXD ----------------
__global__ __launch_bounds__(1024)
void fixup_kernel(const u64* __restrict__ gcand, const u32* __restrict__ ghist,
                  const int* __restrict__ gB1, u64* __restrict__ topkey) {
    __shared__ u64 scand[CAND];        // 48KB
    __shared__ u64 stopk[KPAD];        // 8KB
    int b = blockIdx.x, tid = threadIdx.x;
    const u32* gh = ghist + (size_t)b * NBIN;
    int B1 = gB1[b];
    int Ctot = min((int)gh[B1], CAND);
    for (int i = tid; i < Ctot; i += 1024) scand[i] = gcand[(size_t)b * CAND + i];
    __syncthreads();
    for (int i = tid; i < Ctot; i += 1024) {
        u64 ki = scand[i];
        int bin = (int)(ki >> 36);
        int st = (int)gh[bin + 1];                 // end(bin+1) == start(bin)
        int en = min((int)gh[bin], Ctot);          // segment end
        int pos = st;
        for (int j = st; j < en; ++j) pos += (scand[j] > ki) ? 1 : 0;
        if (pos < MAXD) stopk[pos] = ki;
    }
    __syncthreads();
    if (tid < MAXD) topkey[(size_t)b * KPAD + tid] = stopk[tid];
}

// ---------------- kernel 3: gather winners (wide, pair-split channels) ----------------
__global__ __launch_bounds__(128)
void gather_kernel(Ptrs ptrs, const u64* __restrict__ topkey,
                   float4* __restrict__ traw, float* __restrict__ tscore,
                   float* __restrict__ tclsf, u32* __restrict__ validwords,
                   u32* __restrict__ maxcG) {
    #pragma clang fp contract(off)
    int b = blockIdx.y;
    int tid = threadIdx.x;
    int half = tid & 1;
    int i = blockIdx.x * 64 + (tid >> 1);
    int active = (i < MAXD);

    float score = 0.f;
    float best = -1.0f; int bi = 0;
    float ra = 0.f, rb2 = 0.f;
    int pos = 0, w = 1, s = 0;
    if (active) {
        u64 key = topkey[(size_t)b * KPAD + i];
        int n = 65535 - (int)(key & 0xFFFFull);
        score = __uint_as_float((u32)(key >> 16));
        int mod = (n >= NMOD) ? 1 : 0;
        int nm = n - mod * NMOD;
        int l, hw;
        level_of(nm, l, pos, w, s, hw);
        const float* clsP = ptrs.p[mod * 15 + l];
        const float* regP = ptrs.p[mod * 15 + 10 + l];
        const float* cbp = clsP + (size_t)b * 20 * hw + pos;
        const float* rbp = regP + (size_t)b * 4 * hw + pos;
        float cl[10];
        int c0 = half * 10;
        #pragma unroll
        for (int c = 0; c < 10; ++c) cl[c] = cbp[(size_t)(c0 + c) * hw];
        ra  = rbp[(size_t)(half * 2) * hw];
        rb2 = rbp[(size_t)(half * 2 + 1) * hw];
        #pragma unroll
        for (int c = 0; c < 10; ++c) {
            float p = sigm(cl[c]);
            if (p > best) { best = p; bi = c0 + c; }
        }
    }
    float po  = __shfl_xor(best, 1);
    int   bio = __shfl_xor(bi, 1);
    float rao = __shfl_xor(ra, 1);
    float rbo = __shfl_xor(rb2, 1);
    if (half == 0) { if (po > best)  { best = po; bi = bio; } }
    else           { if (po >= best) { best = po; bi = bio; } }
    float clsf = active ? (float)(bi + 1) : 0.f;
    float r0 = half ? rao : ra,  r1 = half ? rbo : rb2;
    float r2 = half ? ra  : rao, r3 = half ? rb2 : rbo;

    float4 bx = make_float4(0.f, 0.f, 0.f, 0.f);
    if (active) {
        int xi = pos % w, yi = pos / w;
        float cx = (float)(xi * s + (s >> 1));
        float cy = (float)(yi * s + (s >> 1));
        bx.x = cx - r0; bx.y = cy - r1; bx.z = cx + r2; bx.w = cy + r3;
    }
    int valid = active && (score >= 0.05f) && (half == 0);
    float contrib = valid ? fmaxf(0.0f, fmaxf(fmaxf(bx.x, bx.y), fmaxf(bx.z, bx.w))) : 0.0f;
    float red = contrib;
    #pragma unroll
    for (int off = 32; off > 0; off >>= 1) red = fmaxf(red, __shfl_down(red, off));
    if ((tid & 63) == 0) atomicMax(&maxcG[b * 32], __float_as_uint(red));
    u64 ball = __ballot(valid != 0);
    if ((tid & 63) == 0) {
        u32 word = 0;
        for (int j = 0; j < 32; ++j) word |= (u32)((ball >> (2 * j)) & 1ull) << j;
        validwords[b * 32 + blockIdx.x * 2 + (tid >> 6)] = word;
    }
    if (half == 0) {
        size_t oo = (size_t)b * KPAD + i;
        traw[oo] = bx; tscore[oo] = score; tclsf[oo] = clsf;   // zeros for i >= MAXD
    }
}

// ---------------- kernel 4: IoU>0.6 bitmask (256-thread units, upper-triangle) ----------------
#define SW(t) ((((t) & 31) << 3) | ((t) >> 5))
__global__ __launch_bounds__(256)
void mask_kernel(const float4* __restrict__ traw, const float* __restrict__ tclsf,
                 const u32* __restrict__ maxcG, u32* __restrict__ maskG) {
    #pragma clang fp contract(off)
    int u = blockIdx.x, b = blockIdx.y, tid = threadIdx.x;
    int g, wg;
    if (u < 32)      { g = u >> 2;              wg = u & 3; }
    else if (u < 56) { int d = u - 32; g = 8  + d / 3;        wg = 1 + d % 3; }
    else if (u < 72) { int d = u - 56; g = 16 + (d >> 1);     wg = 2 + (d & 1); }
    else             { g = 24 + (u - 72);       wg = 3; }
    int i0 = g * 32, j0 = wg * 256;
    float m1 = __uint_as_float(maxcG[b * 32]) + 1.0f;

    __shared__ float cx1[256], cy1[256], cx2[256], cy2[256], ca[256];
    {
        int t = tid;
        float4 f = traw[(size_t)b * KPAD + j0 + t];
        float o = __fmul_rn(tclsf[(size_t)b * KPAD + j0 + t], m1);
        float ox1 = __fadd_rn(f.x, o), oy1 = __fadd_rn(f.y, o);
        float ox2 = __fadd_rn(f.z, o), oy2 = __fadd_rn(f.w, o);
        float dw = ox2 - ox1 + 1.0f;
        float dh = oy2 - oy1 + 1.0f;
        int ts = SW(t);
        cx1[ts] = ox1; cy1[ts] = oy1; cx2[ts] = ox2; cy2[ts] = oy2;
        ca[ts] = __fmul_rn(dw, dh);
    }
    __syncthreads();

    int ir = tid >> 3, wr = tid & 7;
    int i = i0 + ir;
    float4 fi = traw[(size_t)b * KPAD + i];
    float oi = __fmul_rn(tclsf[(size_t)b * KPAD + i], m1);
    float ix1 = __fadd_rn(fi.x, oi), iy1 = __fadd_rn(fi.y, oi);
    float ix2 = __fadd_rn(fi.z, oi), iy2 = __fadd_rn(fi.w, oi);
    float dwi = ix2 - ix1 + 1.0f, dhi = iy2 - iy1 + 1.0f;
    float ai = __fmul_rn(dwi, dhi);
    u32 bits = 0;
    int jb = wr * 32;
    for (int jj = 0; jj < 32; ++jj) {
        int js = SW(jb + jj);
        float iw = fminf(ix2, cx2[js]) - fmaxf(ix1, cx1[js]) + 1.0f;
        iw = fmaxf(iw, 0.0f);
        float ih = fminf(iy2, cy2[js]) - fmaxf(iy1, cy1[js]) + 1.0f;
        ih = fmaxf(ih, 0.0f);
        float inter = iw * ih;
        float denom = (ai + ca[js]) - inter;
        float iou = inter / denom;
        bits |= (iou > 0.6f) ? (1u << jj) : 0u;
    }
    maskG[((size_t)b * KPAD + i) * 32 + wg * 8 + wr] = bits;
}

// ---------------- kernel 5: blocked greedy scan (32-row blocks, SALU intra chain) ----------------
__global__ __launch_bounds__(512)
void scan_out_kernel(const u32* __restrict__ maskG, const u32* __restrict__ validbits,
                     const float4* __restrict__ traw, const float* __restrict__ tscore,
                     const float* __restrict__ tclsf, float* __restrict__ out) {
    __shared__ u32 sm[KPAD * 32];   // 128KB mask copy, row-swizzled
    __shared__ u32 keeps[32];
    int b = blockIdx.x, tid = threadIdx.x;

    const uint4* s4 = (const uint4*)(maskG + (size_t)b * KPAD * 32);
    uint4* d4 = (uint4*)sm;
    #pragma unroll
    for (int r = 0; r < 16; ++r) {
        int w4 = tid + r * 512;              // uint4 index 0..8191
        int row = w4 >> 3, c4 = w4 & 7;
        d4[(row << 3) | (c4 ^ (row & 7))] = s4[w4];
    }
    __syncthreads();

    if (tid < 64) {
        int lane = tid, lw = lane & 31;
        int rbase = (lane >> 5) << 4;        // lo half: rows 0..15, hi half: 16..31
        u32 vword = validbits[b * 32 + lw];  // lane lw owns valid/removed word lw
        u32 removed = 0u, keepw = 0u;
        for (int g = 0; g < 32; ++g) {
            int i0 = g << 5;
            u32 intra = sm[((i0 + lw) << 5) | (g ^ ((lw & 7) << 2))];
            u32 remg = (u32)__builtin_amdgcn_readlane((int)removed, g);
            u32 valg = (u32)__builtin_amdgcn_readlane((int)vword, g);
            u32 cand = valg & ~remg;
            u32 keep32 = 0u, sup = 0u;
            #pragma unroll
            for (int i = 0; i < 32; ++i) {
                u32 mi = (u32)__builtin_amdgcn_readlane((int)intra, i);
                u32 kb = cand & ~sup & (1u << i);
                sup |= kb ? mi : 0u;
                keep32 |= kb;
            }
            u32 ksh = keep32 >> rbase;
            u32 acc0 = 0u, acc1 = 0u;
            #pragma unroll
            for (int r = 0; r < 16; r += 2) {
                u32 r0 = sm[((i0 + rbase + r)     << 5) | (lw ^ ((r & 7) << 2))];
                u32 r1 = sm[((i0 + rbase + r + 1) << 5) | (lw ^ (((r + 1) & 7) << 2))];
                acc0 |= ((ksh >> r) & 1u)       ? r0 : 0u;
                acc1 |= ((ksh >> (r + 1)) & 1u) ? r1 : 0u;
            }
            u32 acc = acc0 | acc1;
            acc |= (u32)__shfl_xor((int)acc, 32);
            removed |= acc;
            if (lw == g) keepw = keep32;
        }
        if (lane < 32) keeps[lw] = keepw;
    }
    __syncthreads();

    const int BQ = BATCH * MAXD;
    for (int s2 = tid; s2 < MAXD; s2 += 512) {
        u32 kf = (keeps[s2 >> 5] >> (s2 & 31)) & 1u;
        size_t oo = (size_t)b * KPAD + s2;
        float score = tscore[oo];
        float clsf = tclsf[oo];
        float4 bx = traw[oo];
        float x1 = fminf(fmaxf(bx.x, 0.f), 1279.f);
        float y1 = fminf(fmaxf(bx.y, 0.f), 1023.f);
        float x2 = fminf(fmaxf(bx.z, 0.f), 1279.f);
        float y2 = fminf(fmaxf(bx.w, 0.f), 1023.f);
        int base = b * MAXD + s2;
        out[base] = kf ? score : 0.0f;
        out[BQ + base] = kf ? clsf : 0.0f;
        float* ob = out + 2 * BQ + (size_t)base * 4;
        ob[0] = kf ? x1 : 0.f; ob[1] = kf ? y1 : 0.f;
        ob[2] = kf ? x2 : 0.f; ob[3] = kf ? y2 : 0.f;
        out[6 * BQ + base] = kf ? 1.0f : 0.0f;
    }
}

// ---------------- launch (8 nodes) ----------------
extern "C" void kernel_launch(void* const* d_in, const int* in_sizes, int n_in,
                              void* d_out, int out_size, void* d_ws, size_t ws_size,
                              hipStream_t stream) {
    Ptrs ptrs;
    for (int i = 0; i < 30; ++i) ptrs.p[i] = (const float*)d_in[i];

    char* ws = (char*)d_ws;
    u64*    keyAll    = (u64*)   (ws + OFF_KEY);
    u64*    topkey    = (u64*)   (ws + OFF_TOPK);
    float4* traw      = (float4*)(ws + OFF_TRAW);
    float*  tscore    = (float*) (ws + OFF_TSCORE);
    float*  tclsf     = (float*) (ws + OFF_TCLSF);
    u32*    maxcG     = (u32*)   (ws + OFF_MAXC);
    u32*    validbits = (u32*)   (ws + OFF_VALID);
    u32*    maskG     = (u32*)   (ws + OFF_MASK);
    u32*    ghist     = (u32*)   (ws + OFF_GHIST);
    u32*    ghistP    = (u32*)   (ws + OFF_GHISTP);
    int*    gB1       = (int*)   (ws + OFF_GB1);
    u64*    gcand     = (u64*)   (ws + OFF_GCAND);
    float*  out       = (float*)d_out;

    decode_kernel<<<dim3(127, BATCH), 128, 0, stream>>>(ptrs, keyAll);
    hist_kernel<<<dim3(NCHUNK, BATCH), 1024, 0, stream>>>(keyAll, ghistP, maxcG);
    scan_kernel<<<BATCH, 1024, 0, stream>>>(ghistP, ghist, gB1);
    scatter_kernel<<<dim3(NCHUNK, BATCH), 1024, 0, stream>>>(keyAll, ghist, gB1, gcand);
    fixup_kernel<<<BATCH, 1024, 0, stream>>>(gcand, ghist, gB1, topkey);
    gather_kernel<<<dim3(16, BATCH), 128, 0, stream>>>(ptrs, topkey, traw, tscore, tclsf,
                                                       validbits, maxcG);
    mask_kernel<<<dim3(80, BATCH), 256, 0, stream>>>(traw, tclsf, maxcG, maskG);
    scan_out_kernel<<<BATCH, 512, 0, stream>>>(maskG, validbits, traw, tscore, tclsf, out);
}

// Round 6
// 235.122 us; speedup vs baseline: 1.5596x; 1.5596x over previous
//
#include <hip/hip_runtime.h>
#include <hip/hip_bf16.h>

typedef unsigned long long u64;
typedef unsigned int u32;
typedef unsigned short u16;

#define NTOT    54560   // anchors per batch (r + i)
#define NMOD    27280   // anchors per modality
#define BATCH   16
#define KPAD    1024
#define MAXD    1000
#define NBIN    16384   // score-bits >> 16 (16384-bin resolution is load-bearing:
                        // R5 showed NBIN=4096 makes fixup O(n*seg) explode to 134us)
#define CAND    6144    // LDS candidate cap (u64, 48KB)

struct Ptrs { const float* p[30]; };

// ---------------- workspace layout (16B aligned) ----------------
constexpr size_t SZ_KEY   = (size_t)BATCH * NTOT * 8;        // 6.98 MB
constexpr size_t SZ_BIN   = (size_t)BATCH * NTOT * 2;        // 1.75 MB u16 bin sidecar
constexpr size_t SZ_TOPK  = (size_t)BATCH * KPAD * 8;
constexpr size_t SZ_TRAW  = (size_t)BATCH * KPAD * 16;
constexpr size_t SZ_T1    = (size_t)BATCH * KPAD * 4;
constexpr size_t SZ_MAXC  = (size_t)BATCH * 32 * 4;
constexpr size_t SZ_VALID = (size_t)BATCH * 32 * 4;
constexpr size_t SZ_MASK  = (size_t)BATCH * KPAD * 32 * 4;   // 2 MB

constexpr size_t OFF_KEY    = 0;
constexpr size_t OFF_BIN    = OFF_KEY   + SZ_KEY;
constexpr size_t OFF_TOPK   = OFF_BIN   + SZ_BIN;
constexpr size_t OFF_TRAW   = OFF_TOPK  + SZ_TOPK;
constexpr size_t OFF_TSCORE = OFF_TRAW  + SZ_TRAW;
constexpr size_t OFF_TCLSF  = OFF_TSCORE+ SZ_T1;
constexpr size_t OFF_MAXC   = OFF_TCLSF + SZ_T1;
constexpr size_t OFF_VALID  = OFF_MAXC  + SZ_MAXC;
constexpr size_t OFF_MASK   = OFF_VALID + SZ_VALID;

__device__ inline void level_of(int nm, int& l, int& pos, int& w, int& s, int& hw) {
    if (nm < 20480)      { l = 0; pos = nm;         w = 160; s = 8;   hw = 20480; }
    else if (nm < 25600) { l = 1; pos = nm - 20480; w = 80;  s = 16;  hw = 5120; }
    else if (nm < 26880) { l = 2; pos = nm - 25600; w = 40;  s = 32;  hw = 1280; }
    else if (nm < 27200) { l = 3; pos = nm - 26880; w = 20;  s = 64;  hw = 320; }
    else                 { l = 4; pos = nm - 27200; w = 10;  s = 128; hw = 80; }
}

__device__ inline float sigm(float x) { return 1.0f / (1.0f + expf(-x)); }

// async global->LDS DMA, 16B per lane; LDS dest = uniform base + lane*16
__device__ inline void ld_lds16(const float* g, float* l) {
    __builtin_amdgcn_global_load_lds(
        (const __attribute__((address_space(1))) void*)g,
        (__attribute__((address_space(3))) void*)l, 16, 0, 0);
}

// ---------------- kernel 1: decode (512-anchor LDS chunks + quad-split tail) ----------------
// R1-proven structure. Additionally emits the u16 bin sidecar (score bits >> 16)
// so select's histogram pass reads 4x fewer bytes.
__global__ __launch_bounds__(128)
void decode_kernel(Ptrs ptrs, u64* __restrict__ keyAll, u16* __restrict__ binAll) {
    __shared__ float lds[21 * 512];     // 42KB (unused by tail blocks)
    int cc = blockIdx.x;                // 0..99 LDS path, 100..126 tail
    int b = blockIdx.y;

    if (cc >= 100) {
        int t = (cc - 100) * 128 + threadIdx.x;   // 0..3359
        if (t >= 3360) return;
        int mod = t / 1680;
        int tm = t % 1680;
        int q = t & 3;                            // 1680 % 4 == 0
        int nm = 25600 + (tm & ~3);
        int l, pos, w, s, hw;
        level_of(nm, l, pos, w, s, hw);
        (void)w; (void)s;
        const float* clsP = ptrs.p[mod * 15 + l];
        const float* cntP = ptrs.p[mod * 15 + 5 + l];
        const float4* cb = (const float4*)(clsP + (size_t)b * 20 * hw + pos);
        int hw4 = hw >> 2;
        int c0 = q * 5;
        float4 v[5];
        #pragma unroll
        for (int c = 0; c < 5; ++c) v[c] = cb[(size_t)(c0 + c) * hw4];
        float4 cv = *(const float4*)(cntP + (size_t)b * hw + pos);
        float4 mx = v[0];
        #pragma unroll
        for (int c = 1; c < 5; ++c) {
            mx.x = fmaxf(mx.x, v[c].x); mx.y = fmaxf(mx.y, v[c].y);
            mx.z = fmaxf(mx.z, v[c].z); mx.w = fmaxf(mx.w, v[c].w);
        }
        mx.x = fmaxf(mx.x, __shfl_xor(mx.x, 1));
        mx.y = fmaxf(mx.y, __shfl_xor(mx.y, 1));
        mx.z = fmaxf(mx.z, __shfl_xor(mx.z, 1));
        mx.w = fmaxf(mx.w, __shfl_xor(mx.w, 1));
        mx.x = fmaxf(mx.x, __shfl_xor(mx.x, 2));
        mx.y = fmaxf(mx.y, __shfl_xor(mx.y, 2));
        mx.z = fmaxf(mx.z, __shfl_xor(mx.z, 2));
        mx.w = fmaxf(mx.w, __shfl_xor(mx.w, 2));
        float ma = (q & 1) ? ((q & 2) ? mx.w : mx.y) : ((q & 2) ? mx.z : mx.x);
        float ca = (q & 1) ? ((q & 2) ? cv.w : cv.y) : ((q & 2) ? cv.z : cv.x);
        u32 sb = __float_as_uint(sqrtf(__fmul_rn(sigm(ma), sigm(ca))));
        int n = mod * NMOD + nm + q;
        keyAll[(size_t)b * NTOT + n] = ((u64)sb << 16) | (u64)(65535 - n);
        binAll[(size_t)b * NTOT + n] = (u16)(sb >> 16);
        return;
    }

    int mod = cc / 50, c = cc % 50;
    int l     = (c < 40) ? 0 : 1;
    int hw    = (c < 40) ? 20480 : 5120;
    int pos0  = (c < 40) ? c * 512 : (c - 40) * 512;
    int nmb   = (l == 0) ? pos0 : 20480 + pos0;
    const float* clsP = ptrs.p[mod * 15 + l];
    const float* cntP = ptrs.p[mod * 15 + 5 + l];
    int wave = threadIdx.x >> 6, lane = threadIdx.x & 63;

    const float* cbase = clsP + (size_t)b * 20 * hw + pos0 + wave * 256 + lane * 4;
    float* dbase = lds + wave * 256;
    #pragma unroll
    for (int ch = 0; ch < 20; ++ch)
        ld_lds16(cbase + (size_t)ch * hw, dbase + ch * 512);
    ld_lds16(cntP + (size_t)b * hw + pos0 + wave * 256 + lane * 4, dbase + 20 * 512);
    __syncthreads();

    int t = threadIdx.x;                 // 0..127, anchor group pos0 + 4t
    const float4* l4 = (const float4*)lds;
    float4 mx = l4[t];
    #pragma unroll
    for (int ch = 1; ch < 20; ++ch) {
        float4 v = l4[ch * 128 + t];
        mx.x = fmaxf(mx.x, v.x); mx.y = fmaxf(mx.y, v.y);
        mx.z = fmaxf(mx.z, v.z); mx.w = fmaxf(mx.w, v.w);
    }
    float4 cv = l4[20 * 128 + t];

    int n = mod * NMOD + nmb + t * 4;
    u32 s0 = __float_as_uint(sqrtf(__fmul_rn(sigm(mx.x), sigm(cv.x))));
    u32 s1 = __float_as_uint(sqrtf(__fmul_rn(sigm(mx.y), sigm(cv.y))));
    u32 s2 = __float_as_uint(sqrtf(__fmul_rn(sigm(mx.z), sigm(cv.z))));
    u32 s3 = __float_as_uint(sqrtf(__fmul_rn(sigm(mx.w), sigm(cv.w))));
    ulonglong2* ka2 = (ulonglong2*)(keyAll + (size_t)b * NTOT + n);
    ulonglong2 k01, k23;
    k01.x = ((u64)s0 << 16) | (u64)(65535 - n);
    k01.y = ((u64)s1 << 16) | (u64)(65535 - (n + 1));
    k23.x = ((u64)s2 << 16) | (u64)(65535 - (n + 2));
    k23.y = ((u64)s3 << 16) | (u64)(65535 - (n + 3));
    ka2[0] = k01; ka2[1] = k23;
    u64 bw = (u64)(u16)(s0 >> 16) | ((u64)(u16)(s1 >> 16) << 16)
           | ((u64)(u16)(s2 >> 16) << 32) | ((u64)(u16)(s3 >> 16) << 48);
    *(u64*)(binAll + (size_t)b * NTOT + n) = bw;   // n%4==0 -> 8B aligned
}

// ---------------- kernel 2: select (hist + B1 + bucket scatter + in-bin fixup) ----------------
// R1-proven monolithic structure (split variants measured slower, R3-R5).
// Phase 1 now reads the u16 sidecar (109KB/block) instead of keys (436KB).
__global__ __launch_bounds__(1024)
void select_kernel(const u64* __restrict__ keyAll, const u16* __restrict__ binAll,
                   u64* __restrict__ topkey, u32* __restrict__ maxcG) {
    int b = blockIdx.x, tid = threadIdx.x;
    int lane = tid & 63, wid = tid >> 6;
    __shared__ u32 shist[NBIN];        // 64KB: counts -> prefixes -> segment ends
    __shared__ u64 scand[CAND];        // 48KB bin-ordered candidates
    __shared__ u64 stopk[KPAD];        // 8KB sorted top keys
    __shared__ u32 warep[16];
    __shared__ int sB1;

    if (tid == 0) maxcG[b * 32] = 0u;  // gather's atomicMax baseline
    #pragma unroll
    for (int j = 0; j < NBIN / 1024; ++j) shist[tid + j * 1024] = 0u;
    __syncthreads();

    // phase 1: LDS histogram from u16 sidecar (8 bins per uint4 load)
    const uint4* b4 = (const uint4*)(binAll + (size_t)b * NTOT);
    #pragma unroll
    for (int g0 = 0; g0 < 7; ++g0) {
        int g = g0 * 1024 + tid;                   // bin-group index, 8 bins each
        if (g < NTOT / 8) {                        // 54560/8 = 6820 exactly
            uint4 v = b4[g];
            atomicAdd(&shist[v.x & 0xFFFFu], 1u);
            atomicAdd(&shist[v.x >> 16], 1u);
            atomicAdd(&shist[v.y & 0xFFFFu], 1u);
            atomicAdd(&shist[v.y >> 16], 1u);
            atomicAdd(&shist[v.z & 0xFFFFu], 1u);
            atomicAdd(&shist[v.z >> 16], 1u);
            atomicAdd(&shist[v.w & 0xFFFFu], 1u);
            atomicAdd(&shist[v.w >> 16], 1u);
        }
    }
    __syncthreads();

    // phase 2: reverse scan -> B1; write P[bin] (count of keys in bins > bin) back
    u32 loc[16]; u32 sum = 0;
    #pragma unroll
    for (int j = 0; j < 16; ++j) { loc[j] = shist[NBIN - 1 - (tid * 16 + j)]; sum += loc[j]; }
    u32 v = sum;
    #pragma unroll
    for (int off = 1; off < 64; off <<= 1) {
        u32 t2 = (u32)__shfl_up((int)v, off);
        if (lane >= off) v += t2;
    }
    if (lane == 63) warep[wid] = v;
    __syncthreads();
    if (tid < 16) {
        u32 p = warep[tid];
        #pragma unroll
        for (int off = 1; off < 16; off <<= 1) {
            u32 t2 = (u32)__shfl_up((int)p, off);
            if (tid >= off) p += t2;
        }
        warep[tid] = p;
    }
    __syncthreads();
    u32 incl = v + (wid ? warep[wid - 1] : 0u);
    u32 excl = incl - sum;
    if (excl < (u32)MAXD && incl >= (u32)MAXD) {
        u32 c = excl;
        #pragma unroll
        for (int j = 0; j < 16; ++j) {
            c += loc[j];
            if (c >= (u32)MAXD) { sB1 = NBIN - 1 - (tid * 16 + j); break; }
        }
    }
    u32 run = excl;
    #pragma unroll
    for (int j = 0; j < 16; ++j) {
        int bin = NBIN - 1 - (tid * 16 + j);
        shist[bin] = run;
        run += loc[j];
    }
    __syncthreads();
    int B1 = sB1;

    // phase 3: scatter candidates to bin-ordered positions (full keys, L2-hot)
    const u64* keys = keyAll + (size_t)b * NTOT;
    for (int n0 = 0; n0 < NTOT; n0 += 8192) {
        u64 kk[8];
        #pragma unroll
        for (int r = 0; r < 8; ++r) {
            int idx = n0 + r * 1024 + tid;
            kk[r] = (idx < NTOT) ? keys[idx] : 0ull;   // real keys never 0
        }
        #pragma unroll
        for (int r = 0; r < 8; ++r) {
            if (kk[r] != 0ull && (int)(kk[r] >> 32) >= B1) {
                u32 p = atomicAdd(&shist[(u32)(kk[r] >> 32)], 1u);
                if (p < CAND) scand[p] = kk[r];
            }
        }
    }
    __syncthreads();
    int Ctot = min((int)shist[B1], CAND);

    // phase 4: in-bin rank fixup -> exact sorted positions
    for (int i = tid; i < Ctot; i += 1024) {
        u64 ki = scand[i];
        int bin = (int)(ki >> 32);
        int st = (int)shist[bin + 1];              // segment start
        int en = min((int)shist[bin], Ctot);       // segment end
        int pos = st;
        for (int j = st; j < en; ++j) pos += (scand[j] > ki) ? 1 : 0;
        if (pos < MAXD) stopk[pos] = ki;
    }
    __syncthreads();
    if (tid < MAXD) topkey[(size_t)b * KPAD + tid] = stopk[tid];
}

// ---------------- kernel 3: gather winners (wide, pair-split channels) ----------------
__global__ __launch_bounds__(128)
void gather_kernel(Ptrs ptrs, const u64* __restrict__ topkey,
                   float4* __restrict__ traw, float* __restrict__ tscore,
                   float* __restrict__ tclsf, u32* __restrict__ validwords,
                   u32* __restrict__ maxcG) {
    #pragma clang fp contract(off)
    int b = blockIdx.y;
    int tid = threadIdx.x;
    int half = tid & 1;
    int i = blockIdx.x * 64 + (tid >> 1);
    int active = (i < MAXD);

    float score = 0.f;
    float best = -1.0f; int bi = 0;
    float ra = 0.f, rb2 = 0.f;
    int pos = 0, w = 1, s = 0;
    if (active) {
        u64 key = topkey[(size_t)b * KPAD + i];
        int n = 65535 - (int)(key & 0xFFFFull);
        score = __uint_as_float((u32)(key >> 16));
        int mod = (n >= NMOD) ? 1 : 0;
        int nm = n - mod * NMOD;
        int l, hw;
        level_of(nm, l, pos, w, s, hw);
        const float* clsP = ptrs.p[mod * 15 + l];
        const float* regP = ptrs.p[mod * 15 + 10 + l];
        const float* cbp = clsP + (size_t)b * 20 * hw + pos;
        const float* rbp = regP + (size_t)b * 4 * hw + pos;
        float cl[10];
        int c0 = half * 10;
        #pragma unroll
        for (int c = 0; c < 10; ++c) cl[c] = cbp[(size_t)(c0 + c) * hw];
        ra  = rbp[(size_t)(half * 2) * hw];
        rb2 = rbp[(size_t)(half * 2 + 1) * hw];
        #pragma unroll
        for (int c = 0; c < 10; ++c) {
            float p = sigm(cl[c]);
            if (p > best) { best = p; bi = c0 + c; }
        }
    }
    float po  = __shfl_xor(best, 1);
    int   bio = __shfl_xor(bi, 1);
    float rao = __shfl_xor(ra, 1);
    float rbo = __shfl_xor(rb2, 1);
    if (half == 0) { if (po > best)  { best = po; bi = bio; } }
    else           { if (po >= best) { best = po; bi = bio; } }
    float clsf = active ? (float)(bi + 1) : 0.f;
    float r0 = half ? rao : ra,  r1 = half ? rbo : rb2;
    float r2 = half ? ra  : rao, r3 = half ? rb2 : rbo;

    float4 bx = make_float4(0.f, 0.f, 0.f, 0.f);
    if (active) {
        int xi = pos % w, yi = pos / w;
        float cx = (float)(xi * s + (s >> 1));
        float cy = (float)(yi * s + (s >> 1));
        bx.x = cx - r0; bx.y = cy - r1; bx.z = cx + r2; bx.w = cy + r3;
    }
    int valid = active && (score >= 0.05f) && (half == 0);
    float contrib = valid ? fmaxf(0.0f, fmaxf(fmaxf(bx.x, bx.y), fmaxf(bx.z, bx.w))) : 0.0f;
    float red = contrib;
    #pragma unroll
    for (int off = 32; off > 0; off >>= 1) red = fmaxf(red, __shfl_down(red, off));
    if ((tid & 63) == 0) atomicMax(&maxcG[b * 32], __float_as_uint(red));
    u64 ball = __ballot(valid != 0);
    if ((tid & 63) == 0) {
        u32 word = 0;
        for (int j = 0; j < 32; ++j) word |= (u32)((ball >> (2 * j)) & 1ull) << j;
        validwords[b * 32 + blockIdx.x * 2 + (tid >> 6)] = word;
    }
    if (half == 0) {
        size_t oo = (size_t)b * KPAD + i;
        traw[oo] = bx; tscore[oo] = score; tclsf[oo] = clsf;   // zeros for i >= MAXD
    }
}

// ---------------- kernel 4: IoU>0.6 bitmask (256-thread units, upper-triangle) ----------------
#define SW(t) ((((t) & 31) << 3) | ((t) >> 5))
__global__ __launch_bounds__(256)
void mask_kernel(const float4* __restrict__ traw, const float* __restrict__ tclsf,
                 const u32* __restrict__ maxcG, u32* __restrict__ maskG) {
    #pragma clang fp contract(off)
    int u = blockIdx.x, b = blockIdx.y, tid = threadIdx.x;
    int g, wg;
    if (u < 32)      { g = u >> 2;              wg = u & 3; }
    else if (u < 56) { int d = u - 32; g = 8  + d / 3;        wg = 1 + d % 3; }
    else if (u < 72) { int d = u - 56; g = 16 + (d >> 1);     wg = 2 + (d & 1); }
    else             { g = 24 + (u - 72);       wg = 3; }
    int i0 = g * 32, j0 = wg * 256;
    float m1 = __uint_as_float(maxcG[b * 32]) + 1.0f;

    __shared__ float cx1[256], cy1[256], cx2[256], cy2[256], ca[256];
    {
        int t = tid;
        float4 f = traw[(size_t)b * KPAD + j0 + t];
        float o = __fmul_rn(tclsf[(size_t)b * KPAD + j0 + t], m1);
        float ox1 = __fadd_rn(f.x, o), oy1 = __fadd_rn(f.y, o);
        float ox2 = __fadd_rn(f.z, o), oy2 = __fadd_rn(f.w, o);
        float dw = ox2 - ox1 + 1.0f;
        float dh = oy2 - oy1 + 1.0f;
        int ts = SW(t);
        cx1[ts] = ox1; cy1[ts] = oy1; cx2[ts] = ox2; cy2[ts] = oy2;
        ca[ts] = __fmul_rn(dw, dh);
    }
    __syncthreads();

    int ir = tid >> 3, wr = tid & 7;
    int i = i0 + ir;
    float4 fi = traw[(size_t)b * KPAD + i];
    float oi = __fmul_rn(tclsf[(size_t)b * KPAD + i], m1);
    float ix1 = __fadd_rn(fi.x, oi), iy1 = __fadd_rn(fi.y, oi);
    float ix2 = __fadd_rn(fi.z, oi), iy2 = __fadd_rn(fi.w, oi);
    float dwi = ix2 - ix1 + 1.0f, dhi = iy2 - iy1 + 1.0f;
    float ai = __fmul_rn(dwi, dhi);
    u32 bits = 0;
    int jb = wr * 32;
    for (int jj = 0; jj < 32; ++jj) {
        int js = SW(jb + jj);
        float iw = fminf(ix2, cx2[js]) - fmaxf(ix1, cx1[js]) + 1.0f;
        iw = fmaxf(iw, 0.0f);
        float ih = fminf(iy2, cy2[js]) - fmaxf(iy1, cy1[js]) + 1.0f;
        ih = fmaxf(ih, 0.0f);
        float inter = iw * ih;
        float denom = (ai + ca[js]) - inter;
        float iou = inter / denom;
        bits |= (iou > 0.6f) ? (1u << jj) : 0u;
    }
    maskG[((size_t)b * KPAD + i) * 32 + wg * 8 + wr] = bits;
}

// ---------------- kernel 5: blocked greedy scan (32-row blocks, SALU intra chain) ----------------
__global__ __launch_bounds__(512)
void scan_out_kernel(const u32* __restrict__ maskG, const u32* __restrict__ validbits,
                     const float4* __restrict__ traw, const float* __restrict__ tscore,
                     const float* __restrict__ tclsf, float* __restrict__ out) {
    __shared__ u32 sm[KPAD * 32];   // 128KB mask copy, row-swizzled
    __shared__ u32 keeps[32];
    int b = blockIdx.x, tid = threadIdx.x;

    const uint4* s4 = (const uint4*)(maskG + (size_t)b * KPAD * 32);
    uint4* d4 = (uint4*)sm;
    #pragma unroll
    for (int r = 0; r < 16; ++r) {
        int w4 = tid + r * 512;              // uint4 index 0..8191
        int row = w4 >> 3, c4 = w4 & 7;
        d4[(row << 3) | (c4 ^ (row & 7))] = s4[w4];
    }
    __syncthreads();

    if (tid < 64) {
        int lane = tid, lw = lane & 31;
        int rbase = (lane >> 5) << 4;        // lo half: rows 0..15, hi half: 16..31
        u32 vword = validbits[b * 32 + lw];  // lane lw owns valid/removed word lw
        u32 removed = 0u, keepw = 0u;
        for (int g = 0; g < 32; ++g) {
            int i0 = g << 5;
            u32 intra = sm[((i0 + lw) << 5) | (g ^ ((lw & 7) << 2))];
            u32 remg = (u32)__builtin_amdgcn_readlane((int)removed, g);
            u32 valg = (u32)__builtin_amdgcn_readlane((int)vword, g);
            u32 cand = valg & ~remg;
            u32 keep32 = 0u, sup = 0u;
            #pragma unroll
            for (int i = 0; i < 32; ++i) {
                u32 mi = (u32)__builtin_amdgcn_readlane((int)intra, i);
                u32 kb = cand & ~sup & (1u << i);
                sup |= kb ? mi : 0u;
                keep32 |= kb;
            }
            u32 ksh = keep32 >> rbase;
            u32 acc0 = 0u, acc1 = 0u;
            #pragma unroll
            for (int r = 0; r < 16; r += 2) {
                u32 r0 = sm[((i0 + rbase + r)     << 5) | (lw ^ ((r & 7) << 2))];
                u32 r1 = sm[((i0 + rbase + r + 1) << 5) | (lw ^ (((r + 1) & 7) << 2))];
                acc0 |= ((ksh >> r) & 1u)       ? r0 : 0u;
                acc1 |= ((ksh >> (r + 1)) & 1u) ? r1 : 0u;
            }
            u32 acc = acc0 | acc1;
            acc |= (u32)__shfl_xor((int)acc, 32);
            removed |= acc;
            if (lw == g) keepw = keep32;
        }
        if (lane < 32) keeps[lw] = keepw;
    }
    __syncthreads();

    const int BQ = BATCH * MAXD;
    for (int s2 = tid; s2 < MAXD; s2 += 512) {
        u32 kf = (keeps[s2 >> 5] >> (s2 & 31)) & 1u;
        size_t oo = (size_t)b * KPAD + s2;
        float score = tscore[oo];
        float clsf = tclsf[oo];
        float4 bx = traw[oo];
        float x1 = fminf(fmaxf(bx.x, 0.f), 1279.f);
        float y1 = fminf(fmaxf(bx.y, 0.f), 1023.f);
        float x2 = fminf(fmaxf(bx.z, 0.f), 1279.f);
        float y2 = fminf(fmaxf(bx.w, 0.f), 1023.f);
        int base = b * MAXD + s2;
        out[base] = kf ? score : 0.0f;
        out[BQ + base] = kf ? clsf : 0.0f;
        float* ob = out + 2 * BQ + (size_t)base * 4;
        ob[0] = kf ? x1 : 0.f; ob[1] = kf ? y1 : 0.f;
        ob[2] = kf ? x2 : 0.f; ob[3] = kf ? y2 : 0.f;
        out[6 * BQ + base] = kf ? 1.0f : 0.0f;
    }
}

// ---------------- launch (5 nodes, no memsets) ----------------
extern "C" void kernel_launch(void* const* d_in, const int* in_sizes, int n_in,
                              void* d_out, int out_size, void* d_ws, size_t ws_size,
                              hipStream_t stream) {
    Ptrs ptrs;
    for (int i = 0; i < 30; ++i) ptrs.p[i] = (const float*)d_in[i];

    char* ws = (char*)d_ws;
    u64*    keyAll    = (u64*)   (ws + OFF_KEY);
    u16*    binAll    = (u16*)   (ws + OFF_BIN);
    u64*    topkey    = (u64*)   (ws + OFF_TOPK);
    float4* traw      = (float4*)(ws + OFF_TRAW);
    float*  tscore    = (float*) (ws + OFF_TSCORE);
    float*  tclsf     = (float*) (ws + OFF_TCLSF);
    u32*    maxcG     = (u32*)   (ws + OFF_MAXC);
    u32*    validbits = (u32*)   (ws + OFF_VALID);
    u32*    maskG     = (u32*)   (ws + OFF_MASK);
    float*  out       = (float*)d_out;

    decode_kernel<<<dim3(127, BATCH), 128, 0, stream>>>(ptrs, keyAll, binAll);
    select_kernel<<<BATCH, 1024, 0, stream>>>(keyAll, binAll, topkey, maxcG);
    gather_kernel<<<dim3(16, BATCH), 128, 0, stream>>>(ptrs, topkey, traw, tscore, tclsf,
                                                       validbits, maxcG);
    mask_kernel<<<dim3(80, BATCH), 256, 0, stream>>>(traw, tclsf, maxcG, maskG);
    scan_out_kernel<<<BATCH, 512, 0, stream>>>(maskG, validbits, traw, tscore, tclsf, out);
}